// Round 14
// baseline (124.232 us; speedup 1.0000x reference)
//
#include <hip/hip_runtime.h>
#include <hip/hip_cooperative_groups.h>
#include <hip/hip_bf16.h>
#include <math.h>

namespace cg = cooperative_groups;

// max_{n,m} ||L[n]-R[m]||, L,R: [8192][64] fp32.
// R14: single COOPERATIVE kernel (guide §1 sanctions hipLaunchCooperativeKernel).
// Phase A: prepack fp32->bf16 frag-packed + fp32 norms (1 item/thread).
// grid.sync()  — device-scope fence; values replay-deterministic.
// Phase B: 512 blocks, each 8 tiles of 128m x 128n (R6-style dbuf gload_lds
// staging, B-frags in regs once, XCD-local A reuse: xg = bid&7 = XCD).
// grid.sync()
// Phase C: block 0 reduces 512 slots, sqrt -> d_out. One launch total.

typedef __attribute__((ext_vector_type(8)))  short  short8;   // bf16x8 frag
typedef __attribute__((ext_vector_type(4)))  float  f32x4;
typedef __attribute__((ext_vector_type(16))) float  f32x16;   // 32x32 accum

constexpr int D  = 64;
constexpr int NR = 8192;

__device__ __forceinline__ short f2bf(float f) {
    __hip_bfloat16 h = __float2bfloat16(f);
    return __builtin_bit_cast(short, h);
}

// Frag-packed layout: row r, k-chunk kk (16 k's), k-half kh, elem e:
//   short index = ((r>>5)*4 + kk)*512 + (kh*32 + (r&31))*8 + e

__global__ __launch_bounds__(256, 2) void fused_pairdist_kernel(
    const float* __restrict__ L, const float* __restrict__ R,
    short* __restrict__ Apk, short* __restrict__ Bpk,
    float* __restrict__ lsq, float* __restrict__ rsq,
    float* __restrict__ slots, float* __restrict__ out)
{
    __shared__ __align__(16) short A_lds[2][4][4][64][8];   // 2 x 16 KiB dbuf
    __shared__ float wmax_s[4];

    const int tid  = threadIdx.x;
    const int bid  = blockIdx.x;     // 0..511

    // ================= Phase A: prepack (1 item per thread) =================
    {
        const int t = bid * 256 + tid;              // 0..131071
        const int r = t >> 3;
        const int j = t & 7;
        const int kk = j >> 1, kh = j & 1;
        const bool isL = (r < NR);
        const int rr = isL ? r : r - NR;

        const float* src = (isL ? L : R) + (size_t)rr * D + j * 8;
        short* pk = isL ? Apk : Bpk;

        f32x4 v0 = *reinterpret_cast<const f32x4*>(src + 0);
        f32x4 v1 = *reinterpret_cast<const f32x4*>(src + 4);

        float p = 0.f;
        #pragma unroll
        for (int e = 0; e < 4; ++e) { p = fmaf(v0[e], v0[e], p); p = fmaf(v1[e], v1[e], p); }

        short8 w;
        #pragma unroll
        for (int e = 0; e < 4; ++e) { w[e] = f2bf(v0[e]); w[4+e] = f2bf(v1[e]); }
        *reinterpret_cast<short8*>(
            pk + ((size_t)(rr >> 5) * 4 + kk) * 512 + (kh * 32 + (rr & 31)) * 8) = w;

        p += __shfl_xor(p, 1, 64);
        p += __shfl_xor(p, 2, 64);
        p += __shfl_xor(p, 4, 64);
        if (j == 0) (isL ? lsq : rsq)[rr] = p;
    }

    cg::this_grid().sync();

    // ================= Phase B: 8 tiles of 128m x 128n =================
    const int lane = tid & 63;
    const int wave = tid >> 6;
    const int xg = bid & 7;          // A-tile group (xg == XCD under round-robin)
    const int yb = bid >> 3;         // 0..63 -> 128-col chunk of R
    const int wm = wave >> 1;        // 64-row half of 128
    const int wn = wave & 1;         // 64-col half of 128

    // stage tile 0 into buf 0 (16 x 1KB; wave = kk, i = row group)
    {
        const short* At = Apk + (size_t)(xg * 8) * 4 * 2048;
        #pragma unroll
        for (int i = 0; i < 4; ++i)
            __builtin_amdgcn_global_load_lds(
                (const __attribute__((address_space(1))) unsigned int*)
                    (At + ((size_t)i * 4 + wave) * 512 + lane * 8),
                (__attribute__((address_space(3))) unsigned int*)
                    (&A_lds[0][i][wave][0][0]),
                16, 0, 0);
    }

    // B-frags for this wave's 64 cols, all K (8 dwordx4 = 32 VGPR), loaded once
    short8 bf[2][4];
    #pragma unroll
    for (int nj = 0; nj < 2; ++nj)
        #pragma unroll
        for (int kk = 0; kk < 4; ++kk)
            bf[nj][kk] = *reinterpret_cast<const short8*>(
                Bpk + ((size_t)(yb * 4 + wn * 2 + nj) * 4 + kk) * 512 + lane * 8);

    const int col = lane & 31;
    const int h   = lane >> 5;
    float rq[2];
    #pragma unroll
    for (int nj = 0; nj < 2; ++nj)
        rq[nj] = rsq[yb * 128 + (wn * 2 + nj) * 32 + col];

    __syncthreads();   // tile-0 stage complete (vmcnt drained)

    float lmax = 0.f;
    int cur = 0;
    #pragma unroll 1
    for (int t = 0; t < 8; ++t) {
        const int xc = xg * 8 + t;
        if (t < 7) {   // issue next-tile stage; hides under this tile's compute
            const short* At = Apk + (size_t)(xc + 1) * 4 * 2048;
            #pragma unroll
            for (int i = 0; i < 4; ++i)
                __builtin_amdgcn_global_load_lds(
                    (const __attribute__((address_space(1))) unsigned int*)
                        (At + ((size_t)i * 4 + wave) * 512 + lane * 8),
                    (__attribute__((address_space(3))) unsigned int*)
                        (&A_lds[cur ^ 1][i][wave][0][0]),
                    16, 0, 0);
            __builtin_amdgcn_sched_barrier(0);
        }

        f32x16 acc[2][2] = {};
        #pragma unroll
        for (int kk = 0; kk < 4; ++kk) {
            short8 a0 = *reinterpret_cast<const short8*>(&A_lds[cur][wm*2 + 0][kk][lane][0]);
            short8 a1 = *reinterpret_cast<const short8*>(&A_lds[cur][wm*2 + 1][kk][lane][0]);
            acc[0][0] = __builtin_amdgcn_mfma_f32_32x32x16_bf16(a0, bf[0][kk], acc[0][0], 0, 0, 0);
            acc[0][1] = __builtin_amdgcn_mfma_f32_32x32x16_bf16(a0, bf[1][kk], acc[0][1], 0, 0, 0);
            acc[1][0] = __builtin_amdgcn_mfma_f32_32x32x16_bf16(a1, bf[0][kk], acc[1][0], 0, 0, 0);
            acc[1][1] = __builtin_amdgcn_mfma_f32_32x32x16_bf16(a1, bf[1][kk], acc[1][1], 0, 0, 0);
        }

        // epilogue: sq = lsq[row] + rsq[col] - 2*dot, balanced max tree.
        // C layout (32x32): col = lane&31, row = (r&3) + 8*(r>>2) + 4*(lane>>5)
        #pragma unroll
        for (int mi = 0; mi < 2; ++mi) {
            const int rbase = xc * 128 + (wm * 2 + mi) * 32 + 4 * h;
            f32x4 lq0 = *reinterpret_cast<const f32x4*>(lsq + rbase +  0);
            f32x4 lq1 = *reinterpret_cast<const f32x4*>(lsq + rbase +  8);
            f32x4 lq2 = *reinterpret_cast<const f32x4*>(lsq + rbase + 16);
            f32x4 lq3 = *reinterpret_cast<const f32x4*>(lsq + rbase + 24);
            #pragma unroll
            for (int nj = 0; nj < 2; ++nj) {
                float x[16];
                #pragma unroll
                for (int e = 0; e < 4; ++e) {
                    x[0  + e] = fmaf(-2.f, acc[mi][nj][0  + e], lq0[e]);
                    x[4  + e] = fmaf(-2.f, acc[mi][nj][4  + e], lq1[e]);
                    x[8  + e] = fmaf(-2.f, acc[mi][nj][8  + e], lq2[e]);
                    x[12 + e] = fmaf(-2.f, acc[mi][nj][12 + e], lq3[e]);
                }
                float y0 = fmaxf(x[0],  x[1]),  y1 = fmaxf(x[2],  x[3]);
                float y2 = fmaxf(x[4],  x[5]),  y3 = fmaxf(x[6],  x[7]);
                float y4 = fmaxf(x[8],  x[9]),  y5 = fmaxf(x[10], x[11]);
                float y6 = fmaxf(x[12], x[13]), y7 = fmaxf(x[14], x[15]);
                float z0 = fmaxf(y0, y1), z1 = fmaxf(y2, y3);
                float z2 = fmaxf(y4, y5), z3 = fmaxf(y6, y7);
                float m  = fmaxf(fmaxf(z0, z1), fmaxf(z2, z3));
                lmax = fmaxf(lmax, m + rq[nj]);
            }
        }

        __syncthreads();   // next-tile stage complete; safe to flip buffers
        cur ^= 1;
    }

    // block reduce -> slot (contention-free store)
    #pragma unroll
    for (int off = 32; off >= 1; off >>= 1)
        lmax = fmaxf(lmax, __shfl_xor(lmax, off, 64));
    if (lane == 0) wmax_s[wave] = lmax;
    __syncthreads();
    if (tid == 0) {
        float bmax = fmaxf(fmaxf(wmax_s[0], wmax_s[1]), fmaxf(wmax_s[2], wmax_s[3]));
        slots[bid] = fmaxf(bmax, 0.f);
    }

    cg::this_grid().sync();

    // ================= Phase C: block 0 reduces 512 slots =================
    if (bid == 0) {
        float v = fmaxf(slots[tid], slots[tid + 256]);
        #pragma unroll
        for (int off = 32; off >= 1; off >>= 1)
            v = fmaxf(v, __shfl_xor(v, off, 64));
        if (lane == 0) wmax_s[wave] = v;
        __syncthreads();
        if (tid == 0) {
            float m = fmaxf(fmaxf(wmax_s[0], wmax_s[1]), fmaxf(wmax_s[2], wmax_s[3]));
            out[0] = sqrtf(m);
        }
    }
}

extern "C" void kernel_launch(void* const* d_in, const int* in_sizes, int n_in,
                              void* d_out, int out_size, void* d_ws, size_t ws_size,
                              hipStream_t stream) {
    const float* L = (const float*)d_in[0];
    const float* R = (const float*)d_in[1];

    short* Apk = (short*)d_ws;
    short* Bpk = Apk + (size_t)NR * D;           // 524288 shorts each
    float* lsqg = (float*)(Bpk + (size_t)NR * D);
    float* rsqg = lsqg + NR;
    float* slots = rsqg + NR;
    float* outp  = (float*)d_out;

    void* args[] = { (void*)&L, (void*)&R, (void*)&Apk, (void*)&Bpk,
                     (void*)&lsqg, (void*)&rsqg, (void*)&slots, (void*)&outp };
    hipLaunchCooperativeKernel((const void*)fused_pairdist_kernel,
                               dim3(512), dim3(256), args, 0, stream);
}